// Round 5
// baseline (447.116 us; speedup 1.0000x reference)
//
#include <hip/hip_runtime.h>
#include <cstdint>
#include <cstddef>

#define BB 4
#define LL 4096
#define DD 2048
#define EE 8
#define NTOK (BB*LL)   // 16384
#define CAP 2560       // int(1.25 * (B*L/E) + 0.9999)

// ---------------------------------------------------------------------------
// Kernel 1: gating. Block = 256 thr (4 waves), 16 tokens/block (4/wave).
// gate_W staged in 64KB LDS (aliased afterwards for per-token partials).
// Epilogue uses statically-unrolled lane==t so ALL register indices are
// compile-time constants (no scratch spill of the accumulator array).
// ---------------------------------------------------------------------------
__global__ __launch_bounds__(256) void k_gate(
    const float* __restrict__ x, const float* __restrict__ gW,
    const float* __restrict__ gb,
    const float* __restrict__ ew_p, const float* __restrict__ cw_p,
    const float* __restrict__ uw_p, const float* __restrict__ temp_p,
    int* __restrict__ tok_idx, float2* __restrict__ tok_w,
    float* __restrict__ probs_part, float* __restrict__ ent_part)
{
    __shared__ float smem[EE * DD];   // 64KB: gate_W, later reused for partials
    const int tid = threadIdx.x;
    #pragma unroll
    for (int i = 0; i < 16; i++) {
        const int idx = tid + i * 256;           // 4096 float4 total
        ((float4*)smem)[idx] = ((const float4*)gW)[idx];
    }
    __syncthreads();

    const int wave = tid >> 6, lane = tid & 63;
    const int tok0 = blockIdx.x * 16 + wave * 4;

    float acc[EE][4];
    #pragma unroll
    for (int e = 0; e < EE; e++)
        #pragma unroll
        for (int t = 0; t < 4; t++) acc[e][t] = 0.f;

    #pragma unroll
    for (int j = 0; j < 8; j++) {
        const int fi = lane + j * 64;            // float4 index within row
        const float4 xv0 = ((const float4*)(x + (size_t)(tok0 + 0) * DD))[fi];
        const float4 xv1 = ((const float4*)(x + (size_t)(tok0 + 1) * DD))[fi];
        const float4 xv2 = ((const float4*)(x + (size_t)(tok0 + 2) * DD))[fi];
        const float4 xv3 = ((const float4*)(x + (size_t)(tok0 + 3) * DD))[fi];
        #pragma unroll
        for (int e = 0; e < EE; e++) {
            const float4 wv = ((const float4*)(smem + e * DD))[fi];
            acc[e][0] += wv.x*xv0.x + wv.y*xv0.y + wv.z*xv0.z + wv.w*xv0.w;
            acc[e][1] += wv.x*xv1.x + wv.y*xv1.y + wv.z*xv1.z + wv.w*xv1.w;
            acc[e][2] += wv.x*xv2.x + wv.y*xv2.y + wv.z*xv2.z + wv.w*xv2.w;
            acc[e][3] += wv.x*xv3.x + wv.y*xv3.y + wv.z*xv3.z + wv.w*xv3.w;
        }
    }
    // butterfly-reduce all 32 partial dots across the wave
    #pragma unroll
    for (int e = 0; e < EE; e++)
        #pragma unroll
        for (int t = 0; t < 4; t++) {
            float v = acc[e][t];
            v += __shfl_xor(v, 32); v += __shfl_xor(v, 16);
            v += __shfl_xor(v, 8);  v += __shfl_xor(v, 4);
            v += __shfl_xor(v, 2);  v += __shfl_xor(v, 1);
            acc[e][t] = v;
        }
    __syncthreads();   // everyone done reading gate_W from smem; safe to alias

    const float T = temp_p[0];
    #pragma unroll
    for (int t = 0; t < 4; t++) {
        if (lane == t) {                      // t is compile-time: static idx
            const int tok = tok0 + t;
            float li[EE];
            #pragma unroll
            for (int e = 0; e < EE; e++) li[e] = (acc[e][t] + gb[e]) / T;
            float mx = li[0];
            #pragma unroll
            for (int e = 1; e < EE; e++) mx = fmaxf(mx, li[e]);
            float p[EE]; float s = 0.f;
            #pragma unroll
            for (int e = 0; e < EE; e++) { p[e] = expf(li[e] - mx); s += p[e]; }
            const float inv = 1.f / s;
            float ent = 0.f, s1 = 0.f;
            #pragma unroll
            for (int e = 0; e < EE; e++) {
                p[e] *= inv;
                ent -= p[e] * logf(p[e] + 1e-8f);
                s1 += p[e];
            }
            const float m = s1 * 0.125f;
            float sv = 0.f;
            #pragma unroll
            for (int e = 0; e < EE; e++) { const float d = p[e] - m; sv += d * d; }
            const float unc  = sv * (1.f / 7.f);              // ddof=1
            const float conf = 1.f / (unc + 1e-8f);
            const float enrm = 1.f / (1.f + expf(-ent));      // sigmoid(ent/1.0)
            const float z    = ew_p[0]*enrm + cw_p[0]*conf + uw_p[0]*unc;
            const float ad   = 1.f / (1.f + expf(-z));
            const float fac  = 1.f + ad;
            float md[EE]; float ms = 0.f;
            #pragma unroll
            for (int e = 0; e < EE; e++) { md[e] = p[e] * fac; ms += md[e]; }
            const float minv = 1.f / ms;
            #pragma unroll
            for (int e = 0; e < EE; e++) md[e] *= minv;
            // top-2 (strict > keeps lowest index on ties, matching lax.top_k)
            int e0 = 0; float v0 = md[0];
            #pragma unroll
            for (int e = 1; e < EE; e++) { if (md[e] > v0) { v0 = md[e]; e0 = e; } }
            int e1 = 0; float v1 = -1.f;
            #pragma unroll
            for (int e = 0; e < EE; e++) {
                if (e != e0 && md[e] > v1) { v1 = md[e]; e1 = e; }
            }
            const float wn = fmaxf(v0 + v1, 1e-9f);
            tok_idx[tok] = e0 | (e1 << 8);
            tok_w[tok]   = make_float2(v0 / wn, v1 / wn);
            #pragma unroll
            for (int e = 0; e < EE; e++) smem[(wave * 4 + t) * 8 + e] = p[e];
            smem[128 + wave * 4 + t] = ent;
        }
    }
    __syncthreads();
    if (tid < EE) {
        float s = 0.f;
        #pragma unroll
        for (int k = 0; k < 16; k++) s += smem[k * 8 + tid];
        probs_part[blockIdx.x * EE + tid] = s;
    } else if (tid == EE) {
        float s = 0.f;
        #pragma unroll
        for (int k = 0; k < 16; k++) s += smem[128 + k];
        ent_part[blockIdx.x] = s;
    }
}

// ---------------------------------------------------------------------------
// Kernel 2: capacity masking. One wave per (b,e): ballot-prefix scan over L.
// Zeroes dropped weights in tok_w in place, accumulates rawsum[b][e].
// ---------------------------------------------------------------------------
__global__ __launch_bounds__(256) void k_capacity(
    const int* __restrict__ tok_idx, float2* __restrict__ tok_w,
    float* __restrict__ rawsum)
{
    const int lane = threadIdx.x & 63;
    const int wid  = (blockIdx.x << 2) + (threadIdx.x >> 6);  // 0..31
    const int b = wid >> 3, e = wid & 7;
    int run = 0; float wsum = 0.f;
    for (int c = 0; c < LL / 64; c++) {
        const int t = b * LL + (c << 6) + lane;
        const int idx = tok_idx[t];
        const float2 w = tok_w[t];
        const int e0 = idx & 0xff, e1 = (idx >> 8) & 0xff;
        const bool is0 = (e0 == e), is1 = (e1 == e);
        const float wv = is0 ? w.x : (is1 ? w.y : 0.f);
        const bool assigned = (is0 | is1) && (wv > 0.f);
        const unsigned long long m = __ballot(assigned);
        const int rank = run + __popcll(m & ((1ull << lane) - 1ull));
        const bool keep = assigned && (rank < CAP);
        if (assigned && !keep) {
            if (is0) tok_w[t].x = 0.f; else tok_w[t].y = 0.f;
        }
        float kv = keep ? wv : 0.f;
        kv += __shfl_xor(kv, 32); kv += __shfl_xor(kv, 16);
        kv += __shfl_xor(kv, 8);  kv += __shfl_xor(kv, 4);
        kv += __shfl_xor(kv, 2);  kv += __shfl_xor(kv, 1);
        wsum += kv;
        run  += __popcll(m);
    }
    if (lane == 0) rawsum[wid] = wsum;
}

// ---------------------------------------------------------------------------
// Kernel 3a: pooled dispatch partials. Grid (64 lchunks, 4 b, 2 dhalf).
// 64 tokens x 1024 d per block; token top-2 weights expanded to an 8-wide
// dense row in LDS (2KB); acc[8] float4 per thread; partial sums, no atomics.
// ---------------------------------------------------------------------------
__global__ __launch_bounds__(256) void k_pool(
    const float* __restrict__ x, const int* __restrict__ tok_idx,
    const float2* __restrict__ tok_w, float* __restrict__ pool_part)
{
    __shared__ float dl[64 * 8];
    const int tid = threadIdx.x;
    const int lc = blockIdx.x, b = blockIdx.y, db = blockIdx.z;
    const int l0 = lc * 64;
    if (tid < 64) {
        const int t = b * LL + l0 + tid;
        const int pk = tok_idx[t];
        const float2 w = tok_w[t];
        #pragma unroll
        for (int e = 0; e < 8; e++) dl[tid * 8 + e] = 0.f;
        dl[tid * 8 + (pk & 0xff)] = w.x;
        dl[tid * 8 + ((pk >> 8) & 0xff)] = w.y;
    }
    __syncthreads();
    const int d0 = db * 1024 + tid * 4;
    float4 acc[8];
    #pragma unroll
    for (int e = 0; e < 8; e++) acc[e] = make_float4(0.f, 0.f, 0.f, 0.f);
    #pragma unroll 4
    for (int l = 0; l < 64; l++) {
        const float4 xv = *((const float4*)(x + ((size_t)(b * LL + l0 + l)) * DD + d0));
        const float4 wA = *((const float4*)(dl + l * 8));
        const float4 wB = *((const float4*)(dl + l * 8 + 4));
        acc[0].x += wA.x*xv.x; acc[0].y += wA.x*xv.y; acc[0].z += wA.x*xv.z; acc[0].w += wA.x*xv.w;
        acc[1].x += wA.y*xv.x; acc[1].y += wA.y*xv.y; acc[1].z += wA.y*xv.z; acc[1].w += wA.y*xv.w;
        acc[2].x += wA.z*xv.x; acc[2].y += wA.z*xv.y; acc[2].z += wA.z*xv.z; acc[2].w += wA.z*xv.w;
        acc[3].x += wA.w*xv.x; acc[3].y += wA.w*xv.y; acc[3].z += wA.w*xv.z; acc[3].w += wA.w*xv.w;
        acc[4].x += wB.x*xv.x; acc[4].y += wB.x*xv.y; acc[4].z += wB.x*xv.z; acc[4].w += wB.x*xv.w;
        acc[5].x += wB.y*xv.x; acc[5].y += wB.y*xv.y; acc[5].z += wB.y*xv.z; acc[5].w += wB.y*xv.w;
        acc[6].x += wB.z*xv.x; acc[6].y += wB.z*xv.y; acc[6].z += wB.z*xv.z; acc[6].w += wB.z*xv.w;
        acc[7].x += wB.w*xv.x; acc[7].y += wB.w*xv.y; acc[7].z += wB.w*xv.z; acc[7].w += wB.w*xv.w;
    }
    #pragma unroll
    for (int e = 0; e < 8; e++)
        *((float4*)(pool_part + (((size_t)lc * BB + b) * EE + e) * DD + d0)) = acc[e];
}

// Kernel 3b: reduce the 64 partials and divide by counts.
__global__ __launch_bounds__(256) void k_pool_reduce(
    const float* __restrict__ pool_part, const float* __restrict__ rawsum,
    float* __restrict__ ein)
{
    const int d = blockIdx.x * 256 + threadIdx.x;     // 0..2047
    const int e = blockIdx.y, b = blockIdx.z;
    float s = 0.f;
    #pragma unroll 8
    for (int lc = 0; lc < 64; lc++)
        s += pool_part[(((size_t)lc * BB + b) * EE + e) * DD + d];
    const float cnt = fmaxf(rawsum[b * EE + e], 1.f);
    ein[((size_t)b * EE + e) * DD + d] = s / cnt;
}

// ---------------------------------------------------------------------------
// Kernel 4: expert GEMM. One wave per output row f; expert inputs (4 x 2048)
// staged in 32KB LDS; each wave computes 4 dots (one per batch) over W row.
// ---------------------------------------------------------------------------
__global__ __launch_bounds__(256) void k_expert(
    const float* __restrict__ ein, const float* __restrict__ eW,
    const float* __restrict__ eb, float* __restrict__ eout)
{
    __shared__ float inl[BB * DD];  // 32KB
    const int tid = threadIdx.x;
    const int e = blockIdx.x >> 9, fb = blockIdx.x & 511;
    #pragma unroll
    for (int i = 0; i < 8; i++) {
        const int idx = tid + i * 256;                 // float4 index, 2048 total
        const int bb = idx >> 9, rem = idx & 511;
        ((float4*)inl)[idx] = ((const float4*)ein)[((size_t)bb * EE + e) * 512 + rem];
    }
    __syncthreads();
    const int wave = tid >> 6, lane = tid & 63;
    const int f = fb * 4 + wave;
    const float4* Wrow = (const float4*)(eW + ((size_t)e * DD + f) * DD);
    float a0 = 0.f, a1 = 0.f, a2 = 0.f, a3 = 0.f;
    #pragma unroll
    for (int j = 0; j < 8; j++) {
        const int fi = lane + j * 64;
        const float4 wv = Wrow[fi];
        const float4 i0 = ((const float4*)(inl + 0 * DD))[fi];
        const float4 i1 = ((const float4*)(inl + 1 * DD))[fi];
        const float4 i2 = ((const float4*)(inl + 2 * DD))[fi];
        const float4 i3 = ((const float4*)(inl + 3 * DD))[fi];
        a0 += wv.x*i0.x + wv.y*i0.y + wv.z*i0.z + wv.w*i0.w;
        a1 += wv.x*i1.x + wv.y*i1.y + wv.z*i1.z + wv.w*i1.w;
        a2 += wv.x*i2.x + wv.y*i2.y + wv.z*i2.z + wv.w*i2.w;
        a3 += wv.x*i3.x + wv.y*i3.y + wv.z*i3.z + wv.w*i3.w;
    }
    a0 += __shfl_xor(a0, 32); a0 += __shfl_xor(a0, 16); a0 += __shfl_xor(a0, 8);
    a0 += __shfl_xor(a0, 4);  a0 += __shfl_xor(a0, 2);  a0 += __shfl_xor(a0, 1);
    a1 += __shfl_xor(a1, 32); a1 += __shfl_xor(a1, 16); a1 += __shfl_xor(a1, 8);
    a1 += __shfl_xor(a1, 4);  a1 += __shfl_xor(a1, 2);  a1 += __shfl_xor(a1, 1);
    a2 += __shfl_xor(a2, 32); a2 += __shfl_xor(a2, 16); a2 += __shfl_xor(a2, 8);
    a2 += __shfl_xor(a2, 4);  a2 += __shfl_xor(a2, 2);  a2 += __shfl_xor(a2, 1);
    a3 += __shfl_xor(a3, 32); a3 += __shfl_xor(a3, 16); a3 += __shfl_xor(a3, 8);
    a3 += __shfl_xor(a3, 4);  a3 += __shfl_xor(a3, 2);  a3 += __shfl_xor(a3, 1);
    if (lane == 0) {
        const float bias = eb[e * DD + f];
        eout[((size_t)0 * EE + e) * DD + f] = a0 + bias;
        eout[((size_t)1 * EE + e) * DD + f] = a1 + bias;
        eout[((size_t)2 * EE + e) * DD + f] = a2 + bias;
        eout[((size_t)3 * EE + e) * DD + f] = a3 + bias;
    }
}

// ---------------------------------------------------------------------------
// Kernel 5: combine. One block per token: out = w0*eout[e0] + w1*eout[e1].
// ---------------------------------------------------------------------------
__global__ __launch_bounds__(256) void k_combine(
    const int* __restrict__ tok_idx, const float2* __restrict__ tok_w,
    const float* __restrict__ eout, float* __restrict__ out)
{
    const int t = blockIdx.x;
    const int b = t >> 12;
    const int idx = tok_idx[t];
    const float2 w = tok_w[t];
    const int e0 = idx & 0xff, e1 = (idx >> 8) & 0xff;
    const float4* r0 = (const float4*)(eout + ((size_t)b * EE + e0) * DD);
    const float4* r1 = (const float4*)(eout + ((size_t)b * EE + e1) * DD);
    float4* o = (float4*)(out + (size_t)t * DD);
    #pragma unroll
    for (int j = 0; j < 2; j++) {
        const int i = threadIdx.x + j * 256;
        const float4 p0 = r0[i], p1 = r1[i];
        float4 v;
        v.x = w.x * p0.x + w.y * p1.x;
        v.y = w.x * p0.y + w.y * p1.y;
        v.z = w.x * p0.z + w.y * p1.z;
        v.w = w.x * p0.w + w.y * p1.w;
        o[i] = v;
    }
}

// ---------------------------------------------------------------------------
// Kernel 6: aux losses (single block, deterministic).
// ---------------------------------------------------------------------------
__global__ __launch_bounds__(256) void k_aux(
    const float* __restrict__ probs_part, const float* __restrict__ ent_part,
    const float* __restrict__ rawsum, float* __restrict__ aux_out)
{
    __shared__ float sh[256];
    __shared__ float mg[32];
    const int tid = threadIdx.x;
    float es = 0.f;
    for (int i = tid; i < 1024; i += 256) es += ent_part[i];
    sh[tid] = es;
    __syncthreads();
    for (int s = 128; s > 0; s >>= 1) {
        if (tid < s) sh[tid] += sh[tid + s];
        __syncthreads();
    }
    if (tid < 32) {
        const int b = tid >> 3, e = tid & 7;
        float s = 0.f;
        for (int k = 0; k < 256; k++) s += probs_part[((size_t)b * 256 + k) * EE + e];
        mg[tid] = s * (1.f / LL);
    }
    __syncthreads();
    if (tid == 0) {
        const float ment = sh[0] * (1.f / NTOK);
        float msum = 0.f;
        #pragma unroll
        for (int i = 0; i < 32; i++) msum += mg[i];
        const float mm = msum / 32.f;
        float v = 0.f;
        #pragma unroll
        for (int i = 0; i < 32; i++) { const float d = mg[i] - mm; v += d * d; }
        float aux = (v / 32.f) * (float)EE;         // population var * E
        float us = 0.f; float util[8];
        #pragma unroll
        for (int e = 0; e < 8; e++) {
            float u = 0.f;
            #pragma unroll
            for (int b = 0; b < 4; b++) u += rawsum[b * 8 + e];
            u *= (1.f / NTOK);
            util[e] = u; us += u;
        }
        const float um = us / 8.f;
        float uv = 0.f;
        #pragma unroll
        for (int e = 0; e < 8; e++) { const float d = util[e] - um; uv += d * d; }
        uv *= (1.f / 7.f);                          // ddof=1
        aux -= uv * 0.01f;
        const float de = ment - 1.0f;
        aux += de * de * 0.01f;
        aux_out[0] = aux;
    }
}

// ---------------------------------------------------------------------------
extern "C" void kernel_launch(void* const* d_in, const int* in_sizes, int n_in,
                              void* d_out, int out_size, void* d_ws, size_t ws_size,
                              hipStream_t stream)
{
    const float* x  = (const float*)d_in[0];
    const float* gW = (const float*)d_in[1];
    const float* gb = (const float*)d_in[2];
    const float* ew = (const float*)d_in[3];
    const float* cw = (const float*)d_in[4];
    const float* uw = (const float*)d_in[5];
    const float* tp = (const float*)d_in[6];
    const float* eW = (const float*)d_in[7];
    const float* eb = (const float*)d_in[8];
    float* out = (float*)d_out;

    // workspace layout (floats)
    float*  ws         = (float*)d_ws;
    int*    tok_idx    = (int*)ws;                 // 16384 ints
    float2* tok_w      = (float2*)(ws + 16384);    // 16384 float2
    float*  probs_part = ws + 49152;               // 8192
    float*  ent_part   = ws + 57344;               // 1024
    float*  rawsum     = ws + 58368;               // 32
    float*  ein        = ws + 58432;               // 65536
    float*  eout       = ws + 123968;              // 65536
    // 16MB pooling partials live in d_out (fully consumed before k_combine)
    float*  pool_part  = out;

    k_gate<<<1024, 256, 0, stream>>>(x, gW, gb, ew, cw, uw, tp,
                                     tok_idx, tok_w, probs_part, ent_part);
    k_capacity<<<8, 256, 0, stream>>>(tok_idx, tok_w, rawsum);
    k_pool<<<dim3(64, 4, 2), 256, 0, stream>>>(x, tok_idx, tok_w, pool_part);
    k_pool_reduce<<<dim3(8, 8, 4), 256, 0, stream>>>(pool_part, rawsum, ein);
    k_expert<<<4096, 256, 0, stream>>>(ein, eW, eb, eout);
    k_combine<<<NTOK, 256, 0, stream>>>(tok_idx, tok_w, eout, out);
    k_aux<<<1, 256, 0, stream>>>(probs_part, ent_part, rawsum,
                                 out + (size_t)NTOK * DD);
}

// Round 6
// 446.910 us; speedup vs baseline: 1.0005x; 1.0005x over previous
//
#include <hip/hip_runtime.h>
#include <cstdint>
#include <cstddef>

#define BB 4
#define LL 4096
#define DD 2048
#define EE 8
#define NTOK (BB*LL)   // 16384
#define CAP 2560       // int(1.25 * (B*L/E) + 0.9999)

// ---------------------------------------------------------------------------
// Kernel 1: gating. Block = 512 thr (8 waves), 32 tokens/block (4/wave).
// gate_W staged once in 64KB LDS shared by all 8 waves -> 2 blocks/CU =
// 16 waves/CU (vs 8 before; occupancy was the k_gate bottleneck: 17.9%,
// 875 GB/s). Epilogue statically unrolled (lane==t) so all register
// indices are compile-time constants (no scratch).
// ---------------------------------------------------------------------------
__global__ __launch_bounds__(512) void k_gate(
    const float* __restrict__ x, const float* __restrict__ gW,
    const float* __restrict__ gb,
    const float* __restrict__ ew_p, const float* __restrict__ cw_p,
    const float* __restrict__ uw_p, const float* __restrict__ temp_p,
    int* __restrict__ tok_idx, float2* __restrict__ tok_w,
    float* __restrict__ probs_part, float* __restrict__ ent_part)
{
    __shared__ float smem[EE * DD];   // 64KB: gate_W, later reused for partials
    const int tid = threadIdx.x;
    #pragma unroll
    for (int i = 0; i < 8; i++) {
        const int idx = tid + i * 512;           // 4096 float4 total
        ((float4*)smem)[idx] = ((const float4*)gW)[idx];
    }
    __syncthreads();

    const int wave = tid >> 6, lane = tid & 63;
    const int tok0 = blockIdx.x * 32 + wave * 4;

    float acc[EE][4];
    #pragma unroll
    for (int e = 0; e < EE; e++)
        #pragma unroll
        for (int t = 0; t < 4; t++) acc[e][t] = 0.f;

    #pragma unroll
    for (int j = 0; j < 8; j++) {
        const int fi = lane + j * 64;            // float4 index within row
        const float4 xv0 = ((const float4*)(x + (size_t)(tok0 + 0) * DD))[fi];
        const float4 xv1 = ((const float4*)(x + (size_t)(tok0 + 1) * DD))[fi];
        const float4 xv2 = ((const float4*)(x + (size_t)(tok0 + 2) * DD))[fi];
        const float4 xv3 = ((const float4*)(x + (size_t)(tok0 + 3) * DD))[fi];
        #pragma unroll
        for (int e = 0; e < EE; e++) {
            const float4 wv = ((const float4*)(smem + e * DD))[fi];
            acc[e][0] += wv.x*xv0.x + wv.y*xv0.y + wv.z*xv0.z + wv.w*xv0.w;
            acc[e][1] += wv.x*xv1.x + wv.y*xv1.y + wv.z*xv1.z + wv.w*xv1.w;
            acc[e][2] += wv.x*xv2.x + wv.y*xv2.y + wv.z*xv2.z + wv.w*xv2.w;
            acc[e][3] += wv.x*xv3.x + wv.y*xv3.y + wv.z*xv3.z + wv.w*xv3.w;
        }
    }
    // butterfly-reduce all 32 partial dots across the wave
    #pragma unroll
    for (int e = 0; e < EE; e++)
        #pragma unroll
        for (int t = 0; t < 4; t++) {
            float v = acc[e][t];
            v += __shfl_xor(v, 32); v += __shfl_xor(v, 16);
            v += __shfl_xor(v, 8);  v += __shfl_xor(v, 4);
            v += __shfl_xor(v, 2);  v += __shfl_xor(v, 1);
            acc[e][t] = v;
        }
    __syncthreads();   // everyone done reading gate_W from smem; safe to alias

    const float T = temp_p[0];
    #pragma unroll
    for (int t = 0; t < 4; t++) {
        if (lane == t) {                      // t is compile-time: static idx
            const int tok = tok0 + t;
            float li[EE];
            #pragma unroll
            for (int e = 0; e < EE; e++) li[e] = (acc[e][t] + gb[e]) / T;
            float mx = li[0];
            #pragma unroll
            for (int e = 1; e < EE; e++) mx = fmaxf(mx, li[e]);
            float p[EE]; float s = 0.f;
            #pragma unroll
            for (int e = 0; e < EE; e++) { p[e] = expf(li[e] - mx); s += p[e]; }
            const float inv = 1.f / s;
            float ent = 0.f, s1 = 0.f;
            #pragma unroll
            for (int e = 0; e < EE; e++) {
                p[e] *= inv;
                ent -= p[e] * logf(p[e] + 1e-8f);
                s1 += p[e];
            }
            const float m = s1 * 0.125f;
            float sv = 0.f;
            #pragma unroll
            for (int e = 0; e < EE; e++) { const float d = p[e] - m; sv += d * d; }
            const float unc  = sv * (1.f / 7.f);              // ddof=1
            const float conf = 1.f / (unc + 1e-8f);
            const float enrm = 1.f / (1.f + expf(-ent));      // sigmoid(ent/1.0)
            const float z    = ew_p[0]*enrm + cw_p[0]*conf + uw_p[0]*unc;
            const float ad   = 1.f / (1.f + expf(-z));
            const float fac  = 1.f + ad;
            float md[EE]; float ms = 0.f;
            #pragma unroll
            for (int e = 0; e < EE; e++) { md[e] = p[e] * fac; ms += md[e]; }
            const float minv = 1.f / ms;
            #pragma unroll
            for (int e = 0; e < EE; e++) md[e] *= minv;
            // top-2 (strict > keeps lowest index on ties, matching lax.top_k)
            int e0 = 0; float v0 = md[0];
            #pragma unroll
            for (int e = 1; e < EE; e++) { if (md[e] > v0) { v0 = md[e]; e0 = e; } }
            int e1 = 0; float v1 = -1.f;
            #pragma unroll
            for (int e = 0; e < EE; e++) {
                if (e != e0 && md[e] > v1) { v1 = md[e]; e1 = e; }
            }
            const float wn = fmaxf(v0 + v1, 1e-9f);
            tok_idx[tok] = e0 | (e1 << 8);
            tok_w[tok]   = make_float2(v0 / wn, v1 / wn);
            #pragma unroll
            for (int e = 0; e < EE; e++) smem[(wave * 4 + t) * 8 + e] = p[e];
            smem[256 + wave * 4 + t] = ent;
        }
    }
    __syncthreads();
    if (tid < EE) {
        float s = 0.f;
        #pragma unroll
        for (int k = 0; k < 32; k++) s += smem[k * 8 + tid];
        probs_part[blockIdx.x * EE + tid] = s;
    } else if (tid == EE) {
        float s = 0.f;
        #pragma unroll
        for (int k = 0; k < 32; k++) s += smem[256 + k];
        ent_part[blockIdx.x] = s;
    }
}

// ---------------------------------------------------------------------------
// Kernel 2: capacity masking. One wave per (b,e): ballot-prefix scan over L.
// Zeroes dropped weights in tok_w in place, accumulates rawsum[b][e].
// ---------------------------------------------------------------------------
__global__ __launch_bounds__(256) void k_capacity(
    const int* __restrict__ tok_idx, float2* __restrict__ tok_w,
    float* __restrict__ rawsum)
{
    const int lane = threadIdx.x & 63;
    const int wid  = (blockIdx.x << 2) + (threadIdx.x >> 6);  // 0..31
    const int b = wid >> 3, e = wid & 7;
    int run = 0; float wsum = 0.f;
    for (int c = 0; c < LL / 64; c++) {
        const int t = b * LL + (c << 6) + lane;
        const int idx = tok_idx[t];
        const float2 w = tok_w[t];
        const int e0 = idx & 0xff, e1 = (idx >> 8) & 0xff;
        const bool is0 = (e0 == e), is1 = (e1 == e);
        const float wv = is0 ? w.x : (is1 ? w.y : 0.f);
        const bool assigned = (is0 | is1) && (wv > 0.f);
        const unsigned long long m = __ballot(assigned);
        const int rank = run + __popcll(m & ((1ull << lane) - 1ull));
        const bool keep = assigned && (rank < CAP);
        if (assigned && !keep) {
            if (is0) tok_w[t].x = 0.f; else tok_w[t].y = 0.f;
        }
        float kv = keep ? wv : 0.f;
        kv += __shfl_xor(kv, 32); kv += __shfl_xor(kv, 16);
        kv += __shfl_xor(kv, 8);  kv += __shfl_xor(kv, 4);
        kv += __shfl_xor(kv, 2);  kv += __shfl_xor(kv, 1);
        wsum += kv;
        run  += __popcll(m);
    }
    if (lane == 0) rawsum[wid] = wsum;
}

// ---------------------------------------------------------------------------
// Kernel 3a: pooled dispatch partials. Grid (64 lchunks, 4 b, 2 dhalf).
// 64 tokens x 1024 d per block; token top-2 weights expanded to an 8-wide
// dense row in LDS (2KB); acc[8] float4 per thread; partial sums, no atomics.
// ---------------------------------------------------------------------------
__global__ __launch_bounds__(256) void k_pool(
    const float* __restrict__ x, const int* __restrict__ tok_idx,
    const float2* __restrict__ tok_w, float* __restrict__ pool_part)
{
    __shared__ float dl[64 * 8];
    const int tid = threadIdx.x;
    const int lc = blockIdx.x, b = blockIdx.y, db = blockIdx.z;
    const int l0 = lc * 64;
    if (tid < 64) {
        const int t = b * LL + l0 + tid;
        const int pk = tok_idx[t];
        const float2 w = tok_w[t];
        #pragma unroll
        for (int e = 0; e < 8; e++) dl[tid * 8 + e] = 0.f;
        dl[tid * 8 + (pk & 0xff)] = w.x;
        dl[tid * 8 + ((pk >> 8) & 0xff)] = w.y;
    }
    __syncthreads();
    const int d0 = db * 1024 + tid * 4;
    float4 acc[8];
    #pragma unroll
    for (int e = 0; e < 8; e++) acc[e] = make_float4(0.f, 0.f, 0.f, 0.f);
    #pragma unroll 4
    for (int l = 0; l < 64; l++) {
        const float4 xv = *((const float4*)(x + ((size_t)(b * LL + l0 + l)) * DD + d0));
        const float4 wA = *((const float4*)(dl + l * 8));
        const float4 wB = *((const float4*)(dl + l * 8 + 4));
        acc[0].x += wA.x*xv.x; acc[0].y += wA.x*xv.y; acc[0].z += wA.x*xv.z; acc[0].w += wA.x*xv.w;
        acc[1].x += wA.y*xv.x; acc[1].y += wA.y*xv.y; acc[1].z += wA.y*xv.z; acc[1].w += wA.y*xv.w;
        acc[2].x += wA.z*xv.x; acc[2].y += wA.z*xv.y; acc[2].z += wA.z*xv.z; acc[2].w += wA.z*xv.w;
        acc[3].x += wA.w*xv.x; acc[3].y += wA.w*xv.y; acc[3].z += wA.w*xv.z; acc[3].w += wA.w*xv.w;
        acc[4].x += wB.x*xv.x; acc[4].y += wB.x*xv.y; acc[4].z += wB.x*xv.z; acc[4].w += wB.x*xv.w;
        acc[5].x += wB.y*xv.x; acc[5].y += wB.y*xv.y; acc[5].z += wB.y*xv.z; acc[5].w += wB.y*xv.w;
        acc[6].x += wB.z*xv.x; acc[6].y += wB.z*xv.y; acc[6].z += wB.z*xv.z; acc[6].w += wB.z*xv.w;
        acc[7].x += wB.w*xv.x; acc[7].y += wB.w*xv.y; acc[7].z += wB.w*xv.z; acc[7].w += wB.w*xv.w;
    }
    #pragma unroll
    for (int e = 0; e < 8; e++)
        *((float4*)(pool_part + (((size_t)lc * BB + b) * EE + e) * DD + d0)) = acc[e];
}

// Kernel 3b: reduce the 64 partials and divide by counts.
__global__ __launch_bounds__(256) void k_pool_reduce(
    const float* __restrict__ pool_part, const float* __restrict__ rawsum,
    float* __restrict__ ein)
{
    const int d = blockIdx.x * 256 + threadIdx.x;     // 0..2047
    const int e = blockIdx.y, b = blockIdx.z;
    float s = 0.f;
    #pragma unroll 8
    for (int lc = 0; lc < 64; lc++)
        s += pool_part[(((size_t)lc * BB + b) * EE + e) * DD + d];
    const float cnt = fmaxf(rawsum[b * EE + e], 1.f);
    ein[((size_t)b * EE + e) * DD + d] = s / cnt;
}

// ---------------------------------------------------------------------------
// Kernel 4: expert GEMM. One wave per output row f; expert inputs (4 x 2048)
// staged in 32KB LDS; each wave computes 4 dots (one per batch) over W row.
// ---------------------------------------------------------------------------
__global__ __launch_bounds__(256) void k_expert(
    const float* __restrict__ ein, const float* __restrict__ eW,
    const float* __restrict__ eb, float* __restrict__ eout)
{
    __shared__ float inl[BB * DD];  // 32KB
    const int tid = threadIdx.x;
    const int e = blockIdx.x >> 9, fb = blockIdx.x & 511;
    #pragma unroll
    for (int i = 0; i < 8; i++) {
        const int idx = tid + i * 256;                 // float4 index, 2048 total
        const int bb = idx >> 9, rem = idx & 511;
        ((float4*)inl)[idx] = ((const float4*)ein)[((size_t)bb * EE + e) * 512 + rem];
    }
    __syncthreads();
    const int wave = tid >> 6, lane = tid & 63;
    const int f = fb * 4 + wave;
    const float4* Wrow = (const float4*)(eW + ((size_t)e * DD + f) * DD);
    float a0 = 0.f, a1 = 0.f, a2 = 0.f, a3 = 0.f;
    #pragma unroll
    for (int j = 0; j < 8; j++) {
        const int fi = lane + j * 64;
        const float4 wv = Wrow[fi];
        const float4 i0 = ((const float4*)(inl + 0 * DD))[fi];
        const float4 i1 = ((const float4*)(inl + 1 * DD))[fi];
        const float4 i2 = ((const float4*)(inl + 2 * DD))[fi];
        const float4 i3 = ((const float4*)(inl + 3 * DD))[fi];
        a0 += wv.x*i0.x + wv.y*i0.y + wv.z*i0.z + wv.w*i0.w;
        a1 += wv.x*i1.x + wv.y*i1.y + wv.z*i1.z + wv.w*i1.w;
        a2 += wv.x*i2.x + wv.y*i2.y + wv.z*i2.z + wv.w*i2.w;
        a3 += wv.x*i3.x + wv.y*i3.y + wv.z*i3.z + wv.w*i3.w;
    }
    a0 += __shfl_xor(a0, 32); a0 += __shfl_xor(a0, 16); a0 += __shfl_xor(a0, 8);
    a0 += __shfl_xor(a0, 4);  a0 += __shfl_xor(a0, 2);  a0 += __shfl_xor(a0, 1);
    a1 += __shfl_xor(a1, 32); a1 += __shfl_xor(a1, 16); a1 += __shfl_xor(a1, 8);
    a1 += __shfl_xor(a1, 4);  a1 += __shfl_xor(a1, 2);  a1 += __shfl_xor(a1, 1);
    a2 += __shfl_xor(a2, 32); a2 += __shfl_xor(a2, 16); a2 += __shfl_xor(a2, 8);
    a2 += __shfl_xor(a2, 4);  a2 += __shfl_xor(a2, 2);  a2 += __shfl_xor(a2, 1);
    a3 += __shfl_xor(a3, 32); a3 += __shfl_xor(a3, 16); a3 += __shfl_xor(a3, 8);
    a3 += __shfl_xor(a3, 4);  a3 += __shfl_xor(a3, 2);  a3 += __shfl_xor(a3, 1);
    if (lane == 0) {
        const float bias = eb[e * DD + f];
        eout[((size_t)0 * EE + e) * DD + f] = a0 + bias;
        eout[((size_t)1 * EE + e) * DD + f] = a1 + bias;
        eout[((size_t)2 * EE + e) * DD + f] = a2 + bias;
        eout[((size_t)3 * EE + e) * DD + f] = a3 + bias;
    }
}

// ---------------------------------------------------------------------------
// Kernel 5: combine. One block per token: out = w0*eout[e0] + w1*eout[e1].
// ---------------------------------------------------------------------------
__global__ __launch_bounds__(256) void k_combine(
    const int* __restrict__ tok_idx, const float2* __restrict__ tok_w,
    const float* __restrict__ eout, float* __restrict__ out)
{
    const int t = blockIdx.x;
    const int b = t >> 12;
    const int idx = tok_idx[t];
    const float2 w = tok_w[t];
    const int e0 = idx & 0xff, e1 = (idx >> 8) & 0xff;
    const float4* r0 = (const float4*)(eout + ((size_t)b * EE + e0) * DD);
    const float4* r1 = (const float4*)(eout + ((size_t)b * EE + e1) * DD);
    float4* o = (float4*)(out + (size_t)t * DD);
    #pragma unroll
    for (int j = 0; j < 2; j++) {
        const int i = threadIdx.x + j * 256;
        const float4 p0 = r0[i], p1 = r1[i];
        float4 v;
        v.x = w.x * p0.x + w.y * p1.x;
        v.y = w.x * p0.y + w.y * p1.y;
        v.z = w.x * p0.z + w.y * p1.z;
        v.w = w.x * p0.w + w.y * p1.w;
        o[i] = v;
    }
}

// ---------------------------------------------------------------------------
// Kernel 6: aux losses (single block, deterministic).
// probs_part: 512 blocks x 8; ent_part: 512.
// ---------------------------------------------------------------------------
__global__ __launch_bounds__(256) void k_aux(
    const float* __restrict__ probs_part, const float* __restrict__ ent_part,
    const float* __restrict__ rawsum, float* __restrict__ aux_out)
{
    __shared__ float sh[256];
    __shared__ float mg[32];
    const int tid = threadIdx.x;
    float es = 0.f;
    for (int i = tid; i < 512; i += 256) es += ent_part[i];
    sh[tid] = es;
    __syncthreads();
    for (int s = 128; s > 0; s >>= 1) {
        if (tid < s) sh[tid] += sh[tid + s];
        __syncthreads();
    }
    if (tid < 32) {
        const int b = tid >> 3, e = tid & 7;
        float s = 0.f;
        for (int k = 0; k < 128; k++) s += probs_part[((size_t)b * 128 + k) * EE + e];
        mg[tid] = s * (1.f / LL);
    }
    __syncthreads();
    if (tid == 0) {
        const float ment = sh[0] * (1.f / NTOK);
        float msum = 0.f;
        #pragma unroll
        for (int i = 0; i < 32; i++) msum += mg[i];
        const float mm = msum / 32.f;
        float v = 0.f;
        #pragma unroll
        for (int i = 0; i < 32; i++) { const float d = mg[i] - mm; v += d * d; }
        float aux = (v / 32.f) * (float)EE;         // population var * E
        float us = 0.f; float util[8];
        #pragma unroll
        for (int e = 0; e < 8; e++) {
            float u = 0.f;
            #pragma unroll
            for (int b = 0; b < 4; b++) u += rawsum[b * 8 + e];
            u *= (1.f / NTOK);
            util[e] = u; us += u;
        }
        const float um = us / 8.f;
        float uv = 0.f;
        #pragma unroll
        for (int e = 0; e < 8; e++) { const float d = util[e] - um; uv += d * d; }
        uv *= (1.f / 7.f);                          // ddof=1
        aux -= uv * 0.01f;
        const float de = ment - 1.0f;
        aux += de * de * 0.01f;
        aux_out[0] = aux;
    }
}

// ---------------------------------------------------------------------------
extern "C" void kernel_launch(void* const* d_in, const int* in_sizes, int n_in,
                              void* d_out, int out_size, void* d_ws, size_t ws_size,
                              hipStream_t stream)
{
    const float* x  = (const float*)d_in[0];
    const float* gW = (const float*)d_in[1];
    const float* gb = (const float*)d_in[2];
    const float* ew = (const float*)d_in[3];
    const float* cw = (const float*)d_in[4];
    const float* uw = (const float*)d_in[5];
    const float* tp = (const float*)d_in[6];
    const float* eW = (const float*)d_in[7];
    const float* eb = (const float*)d_in[8];
    float* out = (float*)d_out;

    // workspace layout (floats)
    float*  ws         = (float*)d_ws;
    int*    tok_idx    = (int*)ws;                 // 16384 ints
    float2* tok_w      = (float2*)(ws + 16384);    // 16384 float2
    float*  probs_part = ws + 49152;               // 4096 (512 blocks x 8)
    float*  ent_part   = ws + 57344;               // 512
    float*  rawsum     = ws + 58368;               // 32
    float*  ein        = ws + 58432;               // 65536
    float*  eout       = ws + 123968;              // 65536
    // 16MB pooling partials live in d_out (fully consumed before k_combine)
    float*  pool_part  = out;

    k_gate<<<512, 512, 0, stream>>>(x, gW, gb, ew, cw, uw, tp,
                                    tok_idx, tok_w, probs_part, ent_part);
    k_capacity<<<8, 256, 0, stream>>>(tok_idx, tok_w, rawsum);
    k_pool<<<dim3(64, 4, 2), 256, 0, stream>>>(x, tok_idx, tok_w, pool_part);
    k_pool_reduce<<<dim3(8, 8, 4), 256, 0, stream>>>(pool_part, rawsum, ein);
    k_expert<<<4096, 256, 0, stream>>>(ein, eW, eb, eout);
    k_combine<<<NTOK, 256, 0, stream>>>(tok_idx, tok_w, eout, out);
    k_aux<<<1, 256, 0, stream>>>(probs_part, ent_part, rawsum,
                                 out + (size_t)NTOK * DD);
}

// Round 7
// 425.749 us; speedup vs baseline: 1.0502x; 1.0497x over previous
//
#include <hip/hip_runtime.h>
#include <cstdint>
#include <cstddef>

#define BB 4
#define LL 4096
#define DD 2048
#define EE 8
#define NTOK (BB*LL)   // 16384
#define CAP 2560       // int(1.25 * (B*L/E) + 0.9999)

// ---------------------------------------------------------------------------
// Kernel 1a: gate partial GEMM, K-split by 4.
// Grid (1024 token-chunks, 4 kc). Block = 256 thr (4 waves), 16 tokens,
// 512-column slice of gate_W in 16KB LDS. 4096 blocks / small LDS ->
// ~20+ resident waves/CU (vs 6 before: R6 showed Occ 19%, 800 GB/s,
// latency-bound). Writes gpart[tok][kc][e] (2MB).
// ---------------------------------------------------------------------------
__global__ __launch_bounds__(256) void k_gate_part(
    const float* __restrict__ x, const float* __restrict__ gW,
    float* __restrict__ gpart)
{
    __shared__ float gws[EE * 512];   // 16KB slice
    const int tid = threadIdx.x;
    const int kc  = blockIdx.y;
    #pragma unroll
    for (int i = 0; i < 4; i++) {
        const int idx = tid + i * 256;            // f4 idx, 1024 total
        const int e = idx >> 7, c4 = idx & 127;   // 128 f4 per slice row
        ((float4*)gws)[idx] = ((const float4*)gW)[(size_t)e * 512 + kc * 128 + c4];
    }
    __syncthreads();

    const int wave = tid >> 6, lane = tid & 63;
    const int tok0 = blockIdx.x * 16 + wave * 4;

    float acc[EE][4];
    #pragma unroll
    for (int e = 0; e < EE; e++)
        #pragma unroll
        for (int t = 0; t < 4; t++) acc[e][t] = 0.f;

    #pragma unroll
    for (int j = 0; j < 2; j++) {
        const int fi = lane + j * 64;             // f4 idx within slice [0,128)
        const float4 xv0 = ((const float4*)x)[(size_t)(tok0 + 0) * 512 + kc * 128 + fi];
        const float4 xv1 = ((const float4*)x)[(size_t)(tok0 + 1) * 512 + kc * 128 + fi];
        const float4 xv2 = ((const float4*)x)[(size_t)(tok0 + 2) * 512 + kc * 128 + fi];
        const float4 xv3 = ((const float4*)x)[(size_t)(tok0 + 3) * 512 + kc * 128 + fi];
        #pragma unroll
        for (int e = 0; e < EE; e++) {
            const float4 wv = ((const float4*)gws)[e * 128 + fi];
            acc[e][0] += wv.x*xv0.x + wv.y*xv0.y + wv.z*xv0.z + wv.w*xv0.w;
            acc[e][1] += wv.x*xv1.x + wv.y*xv1.y + wv.z*xv1.z + wv.w*xv1.w;
            acc[e][2] += wv.x*xv2.x + wv.y*xv2.y + wv.z*xv2.z + wv.w*xv2.w;
            acc[e][3] += wv.x*xv3.x + wv.y*xv3.y + wv.z*xv3.z + wv.w*xv3.w;
        }
    }
    // butterfly-reduce all 32 partial dots across the wave
    #pragma unroll
    for (int e = 0; e < EE; e++)
        #pragma unroll
        for (int t = 0; t < 4; t++) {
            float v = acc[e][t];
            v += __shfl_xor(v, 32); v += __shfl_xor(v, 16);
            v += __shfl_xor(v, 8);  v += __shfl_xor(v, 4);
            v += __shfl_xor(v, 2);  v += __shfl_xor(v, 1);
            acc[e][t] = v;
        }
    #pragma unroll
    for (int t = 0; t < 4; t++) {
        if (lane == t) {                          // static idx (rule #20)
            const size_t base = (size_t)(tok0 + t) * 8 + kc * 2;   // f4 units
            ((float4*)gpart)[base + 0] = make_float4(acc[0][t], acc[1][t], acc[2][t], acc[3][t]);
            ((float4*)gpart)[base + 1] = make_float4(acc[4][t], acc[5][t], acc[6][t], acc[7][t]);
        }
    }
}

// ---------------------------------------------------------------------------
// Kernel 1b: gate finalize. One thread per token: sum 4 K-partials, then
// softmax/entropy/var/top-2 epilogue (all statically unrolled). Per-block
// (256-token) partial sums of base_probs and entropy for k_aux.
// ---------------------------------------------------------------------------
__global__ __launch_bounds__(256) void k_gate_fin(
    const float* __restrict__ gpart, const float* __restrict__ gb,
    const float* __restrict__ ew_p, const float* __restrict__ cw_p,
    const float* __restrict__ uw_p, const float* __restrict__ temp_p,
    int* __restrict__ tok_idx, float2* __restrict__ tok_w,
    float* __restrict__ probs_part, float* __restrict__ ent_part)
{
    __shared__ float sh[256 * 9];     // 9KB: p[0..7], ent per thread
    const int tid = threadIdx.x;
    const int tok = blockIdx.x * 256 + tid;
    const float T = temp_p[0];

    float4 r[8];
    #pragma unroll
    for (int i = 0; i < 8; i++) r[i] = ((const float4*)gpart)[(size_t)tok * 8 + i];

    float li[EE];
    li[0] = r[0].x + r[2].x + r[4].x + r[6].x;
    li[1] = r[0].y + r[2].y + r[4].y + r[6].y;
    li[2] = r[0].z + r[2].z + r[4].z + r[6].z;
    li[3] = r[0].w + r[2].w + r[4].w + r[6].w;
    li[4] = r[1].x + r[3].x + r[5].x + r[7].x;
    li[5] = r[1].y + r[3].y + r[5].y + r[7].y;
    li[6] = r[1].z + r[3].z + r[5].z + r[7].z;
    li[7] = r[1].w + r[3].w + r[5].w + r[7].w;
    #pragma unroll
    for (int e = 0; e < EE; e++) li[e] = (li[e] + gb[e]) / T;

    float mx = li[0];
    #pragma unroll
    for (int e = 1; e < EE; e++) mx = fmaxf(mx, li[e]);
    float p[EE]; float s = 0.f;
    #pragma unroll
    for (int e = 0; e < EE; e++) { p[e] = expf(li[e] - mx); s += p[e]; }
    const float inv = 1.f / s;
    float ent = 0.f, s1 = 0.f;
    #pragma unroll
    for (int e = 0; e < EE; e++) {
        p[e] *= inv;
        ent -= p[e] * logf(p[e] + 1e-8f);
        s1 += p[e];
    }
    const float m = s1 * 0.125f;
    float sv = 0.f;
    #pragma unroll
    for (int e = 0; e < EE; e++) { const float d = p[e] - m; sv += d * d; }
    const float unc  = sv * (1.f / 7.f);              // ddof=1
    const float conf = 1.f / (unc + 1e-8f);
    const float enrm = 1.f / (1.f + expf(-ent));      // sigmoid(ent/1.0)
    const float z    = ew_p[0]*enrm + cw_p[0]*conf + uw_p[0]*unc;
    const float ad   = 1.f / (1.f + expf(-z));
    const float fac  = 1.f + ad;
    float md[EE]; float ms = 0.f;
    #pragma unroll
    for (int e = 0; e < EE; e++) { md[e] = p[e] * fac; ms += md[e]; }
    const float minv = 1.f / ms;
    #pragma unroll
    for (int e = 0; e < EE; e++) md[e] *= minv;
    // top-2 (strict > keeps lowest index on ties, matching lax.top_k)
    int e0 = 0; float v0 = md[0];
    #pragma unroll
    for (int e = 1; e < EE; e++) { if (md[e] > v0) { v0 = md[e]; e0 = e; } }
    int e1 = 0; float v1 = -1.f;
    #pragma unroll
    for (int e = 0; e < EE; e++) {
        if (e != e0 && md[e] > v1) { v1 = md[e]; e1 = e; }
    }
    const float wn = fmaxf(v0 + v1, 1e-9f);
    tok_idx[tok] = e0 | (e1 << 8);
    tok_w[tok]   = make_float2(v0 / wn, v1 / wn);

    #pragma unroll
    for (int e = 0; e < EE; e++) sh[tid * 9 + e] = p[e];
    sh[tid * 9 + 8] = ent;
    __syncthreads();
    for (int st = 128; st > 0; st >>= 1) {
        if (tid < st) {
            #pragma unroll
            for (int e = 0; e < 9; e++)
                sh[tid * 9 + e] += sh[(tid + st) * 9 + e];
        }
        __syncthreads();
    }
    if (tid < EE) probs_part[blockIdx.x * EE + tid] = sh[tid];
    else if (tid == EE) ent_part[blockIdx.x] = sh[8];
}

// ---------------------------------------------------------------------------
// Kernel 2: capacity masking. One wave per (b,e): ballot-prefix scan over L.
// Zeroes dropped weights in tok_w in place, accumulates rawsum[b][e].
// ---------------------------------------------------------------------------
__global__ __launch_bounds__(256) void k_capacity(
    const int* __restrict__ tok_idx, float2* __restrict__ tok_w,
    float* __restrict__ rawsum)
{
    const int lane = threadIdx.x & 63;
    const int wid  = (blockIdx.x << 2) + (threadIdx.x >> 6);  // 0..31
    const int b = wid >> 3, e = wid & 7;
    int run = 0; float wsum = 0.f;
    for (int c = 0; c < LL / 64; c++) {
        const int t = b * LL + (c << 6) + lane;
        const int idx = tok_idx[t];
        const float2 w = tok_w[t];
        const int e0 = idx & 0xff, e1 = (idx >> 8) & 0xff;
        const bool is0 = (e0 == e), is1 = (e1 == e);
        const float wv = is0 ? w.x : (is1 ? w.y : 0.f);
        const bool assigned = (is0 | is1) && (wv > 0.f);
        const unsigned long long m = __ballot(assigned);
        const int rank = run + __popcll(m & ((1ull << lane) - 1ull));
        const bool keep = assigned && (rank < CAP);
        if (assigned && !keep) {
            if (is0) tok_w[t].x = 0.f; else tok_w[t].y = 0.f;
        }
        float kv = keep ? wv : 0.f;
        kv += __shfl_xor(kv, 32); kv += __shfl_xor(kv, 16);
        kv += __shfl_xor(kv, 8);  kv += __shfl_xor(kv, 4);
        kv += __shfl_xor(kv, 2);  kv += __shfl_xor(kv, 1);
        wsum += kv;
        run  += __popcll(m);
    }
    if (lane == 0) rawsum[wid] = wsum;
}

// ---------------------------------------------------------------------------
// Kernel 3a: pooled dispatch partials. Grid (64 lchunks, 4 b, 2 dhalf).
// 64 tokens x 1024 d per block; token top-2 weights expanded to an 8-wide
// dense row in LDS (2KB); acc[8] float4 per thread; partial sums, no atomics.
// ---------------------------------------------------------------------------
__global__ __launch_bounds__(256) void k_pool(
    const float* __restrict__ x, const int* __restrict__ tok_idx,
    const float2* __restrict__ tok_w, float* __restrict__ pool_part)
{
    __shared__ float dl[64 * 8];
    const int tid = threadIdx.x;
    const int lc = blockIdx.x, b = blockIdx.y, db = blockIdx.z;
    const int l0 = lc * 64;
    if (tid < 64) {
        const int t = b * LL + l0 + tid;
        const int pk = tok_idx[t];
        const float2 w = tok_w[t];
        #pragma unroll
        for (int e = 0; e < 8; e++) dl[tid * 8 + e] = 0.f;
        dl[tid * 8 + (pk & 0xff)] = w.x;
        dl[tid * 8 + ((pk >> 8) & 0xff)] = w.y;
    }
    __syncthreads();
    const int d0 = db * 1024 + tid * 4;
    float4 acc[8];
    #pragma unroll
    for (int e = 0; e < 8; e++) acc[e] = make_float4(0.f, 0.f, 0.f, 0.f);
    #pragma unroll 4
    for (int l = 0; l < 64; l++) {
        const float4 xv = *((const float4*)(x + ((size_t)(b * LL + l0 + l)) * DD + d0));
        const float4 wA = *((const float4*)(dl + l * 8));
        const float4 wB = *((const float4*)(dl + l * 8 + 4));
        acc[0].x += wA.x*xv.x; acc[0].y += wA.x*xv.y; acc[0].z += wA.x*xv.z; acc[0].w += wA.x*xv.w;
        acc[1].x += wA.y*xv.x; acc[1].y += wA.y*xv.y; acc[1].z += wA.y*xv.z; acc[1].w += wA.y*xv.w;
        acc[2].x += wA.z*xv.x; acc[2].y += wA.z*xv.y; acc[2].z += wA.z*xv.z; acc[2].w += wA.z*xv.w;
        acc[3].x += wA.w*xv.x; acc[3].y += wA.w*xv.y; acc[3].z += wA.w*xv.z; acc[3].w += wA.w*xv.w;
        acc[4].x += wB.x*xv.x; acc[4].y += wB.x*xv.y; acc[4].z += wB.x*xv.z; acc[4].w += wB.x*xv.w;
        acc[5].x += wB.y*xv.x; acc[5].y += wB.y*xv.y; acc[5].z += wB.y*xv.z; acc[5].w += wB.y*xv.w;
        acc[6].x += wB.z*xv.x; acc[6].y += wB.z*xv.y; acc[6].z += wB.z*xv.z; acc[6].w += wB.z*xv.w;
        acc[7].x += wB.w*xv.x; acc[7].y += wB.w*xv.y; acc[7].z += wB.w*xv.z; acc[7].w += wB.w*xv.w;
    }
    #pragma unroll
    for (int e = 0; e < 8; e++)
        *((float4*)(pool_part + (((size_t)lc * BB + b) * EE + e) * DD + d0)) = acc[e];
}

// Kernel 3b: reduce the 64 partials and divide by counts.
__global__ __launch_bounds__(256) void k_pool_reduce(
    const float* __restrict__ pool_part, const float* __restrict__ rawsum,
    float* __restrict__ ein)
{
    const int d = blockIdx.x * 256 + threadIdx.x;     // 0..2047
    const int e = blockIdx.y, b = blockIdx.z;
    float s = 0.f;
    #pragma unroll 8
    for (int lc = 0; lc < 64; lc++)
        s += pool_part[(((size_t)lc * BB + b) * EE + e) * DD + d];
    const float cnt = fmaxf(rawsum[b * EE + e], 1.f);
    ein[((size_t)b * EE + e) * DD + d] = s / cnt;
}

// ---------------------------------------------------------------------------
// Kernel 4: expert GEMM. One wave per output row f; expert inputs (4 x 2048)
// staged in 32KB LDS; each wave computes 4 dots (one per batch) over W row.
// ---------------------------------------------------------------------------
__global__ __launch_bounds__(256) void k_expert(
    const float* __restrict__ ein, const float* __restrict__ eW,
    const float* __restrict__ eb, float* __restrict__ eout)
{
    __shared__ float inl[BB * DD];  // 32KB
    const int tid = threadIdx.x;
    const int e = blockIdx.x >> 9, fb = blockIdx.x & 511;
    #pragma unroll
    for (int i = 0; i < 8; i++) {
        const int idx = tid + i * 256;                 // float4 index, 2048 total
        const int bb = idx >> 9, rem = idx & 511;
        ((float4*)inl)[idx] = ((const float4*)ein)[((size_t)bb * EE + e) * 512 + rem];
    }
    __syncthreads();
    const int wave = tid >> 6, lane = tid & 63;
    const int f = fb * 4 + wave;
    const float4* Wrow = (const float4*)(eW + ((size_t)e * DD + f) * DD);
    float a0 = 0.f, a1 = 0.f, a2 = 0.f, a3 = 0.f;
    #pragma unroll
    for (int j = 0; j < 8; j++) {
        const int fi = lane + j * 64;
        const float4 wv = Wrow[fi];
        const float4 i0 = ((const float4*)(inl + 0 * DD))[fi];
        const float4 i1 = ((const float4*)(inl + 1 * DD))[fi];
        const float4 i2 = ((const float4*)(inl + 2 * DD))[fi];
        const float4 i3 = ((const float4*)(inl + 3 * DD))[fi];
        a0 += wv.x*i0.x + wv.y*i0.y + wv.z*i0.z + wv.w*i0.w;
        a1 += wv.x*i1.x + wv.y*i1.y + wv.z*i1.z + wv.w*i1.w;
        a2 += wv.x*i2.x + wv.y*i2.y + wv.z*i2.z + wv.w*i2.w;
        a3 += wv.x*i3.x + wv.y*i3.y + wv.z*i3.z + wv.w*i3.w;
    }
    a0 += __shfl_xor(a0, 32); a0 += __shfl_xor(a0, 16); a0 += __shfl_xor(a0, 8);
    a0 += __shfl_xor(a0, 4);  a0 += __shfl_xor(a0, 2);  a0 += __shfl_xor(a0, 1);
    a1 += __shfl_xor(a1, 32); a1 += __shfl_xor(a1, 16); a1 += __shfl_xor(a1, 8);
    a1 += __shfl_xor(a1, 4);  a1 += __shfl_xor(a1, 2);  a1 += __shfl_xor(a1, 1);
    a2 += __shfl_xor(a2, 32); a2 += __shfl_xor(a2, 16); a2 += __shfl_xor(a2, 8);
    a2 += __shfl_xor(a2, 4);  a2 += __shfl_xor(a2, 2);  a2 += __shfl_xor(a2, 1);
    a3 += __shfl_xor(a3, 32); a3 += __shfl_xor(a3, 16); a3 += __shfl_xor(a3, 8);
    a3 += __shfl_xor(a3, 4);  a3 += __shfl_xor(a3, 2);  a3 += __shfl_xor(a3, 1);
    if (lane == 0) {
        const float bias = eb[e * DD + f];
        eout[((size_t)0 * EE + e) * DD + f] = a0 + bias;
        eout[((size_t)1 * EE + e) * DD + f] = a1 + bias;
        eout[((size_t)2 * EE + e) * DD + f] = a2 + bias;
        eout[((size_t)3 * EE + e) * DD + f] = a3 + bias;
    }
}

// ---------------------------------------------------------------------------
// Kernel 5: combine. One block per token: out = w0*eout[e0] + w1*eout[e1].
// ---------------------------------------------------------------------------
__global__ __launch_bounds__(256) void k_combine(
    const int* __restrict__ tok_idx, const float2* __restrict__ tok_w,
    const float* __restrict__ eout, float* __restrict__ out)
{
    const int t = blockIdx.x;
    const int b = t >> 12;
    const int idx = tok_idx[t];
    const float2 w = tok_w[t];
    const int e0 = idx & 0xff, e1 = (idx >> 8) & 0xff;
    const float4* r0 = (const float4*)(eout + ((size_t)b * EE + e0) * DD);
    const float4* r1 = (const float4*)(eout + ((size_t)b * EE + e1) * DD);
    float4* o = (float4*)(out + (size_t)t * DD);
    #pragma unroll
    for (int j = 0; j < 2; j++) {
        const int i = threadIdx.x + j * 256;
        const float4 p0 = r0[i], p1 = r1[i];
        float4 v;
        v.x = w.x * p0.x + w.y * p1.x;
        v.y = w.x * p0.y + w.y * p1.y;
        v.z = w.x * p0.z + w.y * p1.z;
        v.w = w.x * p0.w + w.y * p1.w;
        o[i] = v;
    }
}

// ---------------------------------------------------------------------------
// Kernel 6: aux losses (single block, deterministic).
// probs_part: 64 blocks x 8; ent_part: 64.
// ---------------------------------------------------------------------------
__global__ __launch_bounds__(256) void k_aux(
    const float* __restrict__ probs_part, const float* __restrict__ ent_part,
    const float* __restrict__ rawsum, float* __restrict__ aux_out)
{
    __shared__ float sh[256];
    __shared__ float mg[32];
    const int tid = threadIdx.x;
    float es = 0.f;
    if (tid < 64) es = ent_part[tid];
    sh[tid] = es;
    __syncthreads();
    for (int s = 128; s > 0; s >>= 1) {
        if (tid < s) sh[tid] += sh[tid + s];
        __syncthreads();
    }
    if (tid < 32) {
        const int b = tid >> 3, e = tid & 7;
        float s = 0.f;
        #pragma unroll
        for (int k = 0; k < 16; k++) s += probs_part[((size_t)b * 16 + k) * EE + e];
        mg[tid] = s * (1.f / LL);
    }
    __syncthreads();
    if (tid == 0) {
        const float ment = sh[0] * (1.f / NTOK);
        float msum = 0.f;
        #pragma unroll
        for (int i = 0; i < 32; i++) msum += mg[i];
        const float mm = msum / 32.f;
        float v = 0.f;
        #pragma unroll
        for (int i = 0; i < 32; i++) { const float d = mg[i] - mm; v += d * d; }
        float aux = (v / 32.f) * (float)EE;         // population var * E
        float us = 0.f; float util[8];
        #pragma unroll
        for (int e = 0; e < 8; e++) {
            float u = 0.f;
            #pragma unroll
            for (int b = 0; b < 4; b++) u += rawsum[b * 8 + e];
            u *= (1.f / NTOK);
            util[e] = u; us += u;
        }
        const float um = us / 8.f;
        float uv = 0.f;
        #pragma unroll
        for (int e = 0; e < 8; e++) { const float d = util[e] - um; uv += d * d; }
        uv *= (1.f / 7.f);                          // ddof=1
        aux -= uv * 0.01f;
        const float de = ment - 1.0f;
        aux += de * de * 0.01f;
        aux_out[0] = aux;
    }
}

// ---------------------------------------------------------------------------
extern "C" void kernel_launch(void* const* d_in, const int* in_sizes, int n_in,
                              void* d_out, int out_size, void* d_ws, size_t ws_size,
                              hipStream_t stream)
{
    const float* x  = (const float*)d_in[0];
    const float* gW = (const float*)d_in[1];
    const float* gb = (const float*)d_in[2];
    const float* ew = (const float*)d_in[3];
    const float* cw = (const float*)d_in[4];
    const float* uw = (const float*)d_in[5];
    const float* tp = (const float*)d_in[6];
    const float* eW = (const float*)d_in[7];
    const float* eb = (const float*)d_in[8];
    float* out = (float*)d_out;

    // workspace layout (floats)
    float*  ws         = (float*)d_ws;
    int*    tok_idx    = (int*)ws;                 // 16384 ints
    float2* tok_w      = (float2*)(ws + 16384);    // 16384 float2
    float*  probs_part = ws + 49152;               // 512 (64 blocks x 8)
    float*  ent_part   = ws + 57344;               // 64
    float*  rawsum     = ws + 58368;               // 32
    float*  ein        = ws + 58432;               // 65536
    float*  eout       = ws + 123968;              // 65536
    float*  gpart      = ws + 189504;              // 524288 (2MB: tok x kc x e)
    // 16MB pooling partials live in d_out (fully consumed before k_combine)
    float*  pool_part  = out;

    k_gate_part<<<dim3(1024, 4), 256, 0, stream>>>(x, gW, gpart);
    k_gate_fin<<<64, 256, 0, stream>>>(gpart, gb, ew, cw, uw, tp,
                                       tok_idx, tok_w, probs_part, ent_part);
    k_capacity<<<8, 256, 0, stream>>>(tok_idx, tok_w, rawsum);
    k_pool<<<dim3(64, 4, 2), 256, 0, stream>>>(x, tok_idx, tok_w, pool_part);
    k_pool_reduce<<<dim3(8, 8, 4), 256, 0, stream>>>(pool_part, rawsum, ein);
    k_expert<<<4096, 256, 0, stream>>>(ein, eW, eb, eout);
    k_combine<<<NTOK, 256, 0, stream>>>(tok_idx, tok_w, eout, out);
    k_aux<<<1, 256, 0, stream>>>(probs_part, ent_part, rawsum,
                                 out + (size_t)NTOK * DD);
}

// Round 8
// 425.634 us; speedup vs baseline: 1.0505x; 1.0003x over previous
//
#include <hip/hip_runtime.h>
#include <cstdint>
#include <cstddef>

#define BB 4
#define LL 4096
#define DD 2048
#define EE 8
#define NTOK (BB*LL)   // 16384
#define CAP 2560       // int(1.25 * (B*L/E) + 0.9999)
#define NLC 128        // pool l-chunks (32 tokens each)

// ---------------------------------------------------------------------------
// Kernel 1a: gate partial GEMM, K-split by 4.
// Grid (1024 token-chunks, 4 kc). Block = 256 thr (4 waves), 16 tokens,
// 512-column slice of gate_W in 16KB LDS. Writes gpart[tok][kc][e] (2MB).
// ---------------------------------------------------------------------------
__global__ __launch_bounds__(256) void k_gate_part(
    const float* __restrict__ x, const float* __restrict__ gW,
    float* __restrict__ gpart)
{
    __shared__ float gws[EE * 512];   // 16KB slice
    const int tid = threadIdx.x;
    const int kc  = blockIdx.y;
    #pragma unroll
    for (int i = 0; i < 4; i++) {
        const int idx = tid + i * 256;            // f4 idx, 1024 total
        const int e = idx >> 7, c4 = idx & 127;   // 128 f4 per slice row
        ((float4*)gws)[idx] = ((const float4*)gW)[(size_t)e * 512 + kc * 128 + c4];
    }
    __syncthreads();

    const int wave = tid >> 6, lane = tid & 63;
    const int tok0 = blockIdx.x * 16 + wave * 4;

    float acc[EE][4];
    #pragma unroll
    for (int e = 0; e < EE; e++)
        #pragma unroll
        for (int t = 0; t < 4; t++) acc[e][t] = 0.f;

    #pragma unroll
    for (int j = 0; j < 2; j++) {
        const int fi = lane + j * 64;             // f4 idx within slice [0,128)
        const float4 xv0 = ((const float4*)x)[(size_t)(tok0 + 0) * 512 + kc * 128 + fi];
        const float4 xv1 = ((const float4*)x)[(size_t)(tok0 + 1) * 512 + kc * 128 + fi];
        const float4 xv2 = ((const float4*)x)[(size_t)(tok0 + 2) * 512 + kc * 128 + fi];
        const float4 xv3 = ((const float4*)x)[(size_t)(tok0 + 3) * 512 + kc * 128 + fi];
        #pragma unroll
        for (int e = 0; e < EE; e++) {
            const float4 wv = ((const float4*)gws)[e * 128 + fi];
            acc[e][0] += wv.x*xv0.x + wv.y*xv0.y + wv.z*xv0.z + wv.w*xv0.w;
            acc[e][1] += wv.x*xv1.x + wv.y*xv1.y + wv.z*xv1.z + wv.w*xv1.w;
            acc[e][2] += wv.x*xv2.x + wv.y*xv2.y + wv.z*xv2.z + wv.w*xv2.w;
            acc[e][3] += wv.x*xv3.x + wv.y*xv3.y + wv.z*xv3.z + wv.w*xv3.w;
        }
    }
    // butterfly-reduce all 32 partial dots across the wave
    #pragma unroll
    for (int e = 0; e < EE; e++)
        #pragma unroll
        for (int t = 0; t < 4; t++) {
            float v = acc[e][t];
            v += __shfl_xor(v, 32); v += __shfl_xor(v, 16);
            v += __shfl_xor(v, 8);  v += __shfl_xor(v, 4);
            v += __shfl_xor(v, 2);  v += __shfl_xor(v, 1);
            acc[e][t] = v;
        }
    #pragma unroll
    for (int t = 0; t < 4; t++) {
        if (lane == t) {                          // static idx (rule #20)
            const size_t base = (size_t)(tok0 + t) * 8 + kc * 2;   // f4 units
            ((float4*)gpart)[base + 0] = make_float4(acc[0][t], acc[1][t], acc[2][t], acc[3][t]);
            ((float4*)gpart)[base + 1] = make_float4(acc[4][t], acc[5][t], acc[6][t], acc[7][t]);
        }
    }
}

// ---------------------------------------------------------------------------
// Kernel 1b: gate finalize. One thread per token: sum 4 K-partials, then
// softmax/entropy/var/top-2 epilogue (all statically unrolled). Per-block
// (256-token) partial sums of base_probs and entropy for aux.
// ---------------------------------------------------------------------------
__global__ __launch_bounds__(256) void k_gate_fin(
    const float* __restrict__ gpart, const float* __restrict__ gb,
    const float* __restrict__ ew_p, const float* __restrict__ cw_p,
    const float* __restrict__ uw_p, const float* __restrict__ temp_p,
    int* __restrict__ tok_idx, float2* __restrict__ tok_w,
    float* __restrict__ probs_part, float* __restrict__ ent_part)
{
    __shared__ float sh[256 * 9];     // 9KB: p[0..7], ent per thread
    const int tid = threadIdx.x;
    const int tok = blockIdx.x * 256 + tid;
    const float T = temp_p[0];

    float4 r[8];
    #pragma unroll
    for (int i = 0; i < 8; i++) r[i] = ((const float4*)gpart)[(size_t)tok * 8 + i];

    float li[EE];
    li[0] = r[0].x + r[2].x + r[4].x + r[6].x;
    li[1] = r[0].y + r[2].y + r[4].y + r[6].y;
    li[2] = r[0].z + r[2].z + r[4].z + r[6].z;
    li[3] = r[0].w + r[2].w + r[4].w + r[6].w;
    li[4] = r[1].x + r[3].x + r[5].x + r[7].x;
    li[5] = r[1].y + r[3].y + r[5].y + r[7].y;
    li[6] = r[1].z + r[3].z + r[5].z + r[7].z;
    li[7] = r[1].w + r[3].w + r[5].w + r[7].w;
    #pragma unroll
    for (int e = 0; e < EE; e++) li[e] = (li[e] + gb[e]) / T;

    float mx = li[0];
    #pragma unroll
    for (int e = 1; e < EE; e++) mx = fmaxf(mx, li[e]);
    float p[EE]; float s = 0.f;
    #pragma unroll
    for (int e = 0; e < EE; e++) { p[e] = expf(li[e] - mx); s += p[e]; }
    const float inv = 1.f / s;
    float ent = 0.f, s1 = 0.f;
    #pragma unroll
    for (int e = 0; e < EE; e++) {
        p[e] *= inv;
        ent -= p[e] * logf(p[e] + 1e-8f);
        s1 += p[e];
    }
    const float m = s1 * 0.125f;
    float sv = 0.f;
    #pragma unroll
    for (int e = 0; e < EE; e++) { const float d = p[e] - m; sv += d * d; }
    const float unc  = sv * (1.f / 7.f);              // ddof=1
    const float conf = 1.f / (unc + 1e-8f);
    const float enrm = 1.f / (1.f + expf(-ent));      // sigmoid(ent/1.0)
    const float z    = ew_p[0]*enrm + cw_p[0]*conf + uw_p[0]*unc;
    const float ad   = 1.f / (1.f + expf(-z));
    const float fac  = 1.f + ad;
    float md[EE]; float ms = 0.f;
    #pragma unroll
    for (int e = 0; e < EE; e++) { md[e] = p[e] * fac; ms += md[e]; }
    const float minv = 1.f / ms;
    #pragma unroll
    for (int e = 0; e < EE; e++) md[e] *= minv;
    // top-2 (strict > keeps lowest index on ties, matching lax.top_k)
    int e0 = 0; float v0 = md[0];
    #pragma unroll
    for (int e = 1; e < EE; e++) { if (md[e] > v0) { v0 = md[e]; e0 = e; } }
    int e1 = 0; float v1 = -1.f;
    #pragma unroll
    for (int e = 0; e < EE; e++) {
        if (e != e0 && md[e] > v1) { v1 = md[e]; e1 = e; }
    }
    const float wn = fmaxf(v0 + v1, 1e-9f);
    tok_idx[tok] = e0 | (e1 << 8);
    tok_w[tok]   = make_float2(v0 / wn, v1 / wn);

    #pragma unroll
    for (int e = 0; e < EE; e++) sh[tid * 9 + e] = p[e];
    sh[tid * 9 + 8] = ent;
    __syncthreads();
    for (int st = 128; st > 0; st >>= 1) {
        if (tid < st) {
            #pragma unroll
            for (int e = 0; e < 9; e++)
                sh[tid * 9 + e] += sh[(tid + st) * 9 + e];
        }
        __syncthreads();
    }
    if (tid < EE) probs_part[blockIdx.x * EE + tid] = sh[tid];
    else if (tid == EE) ent_part[blockIdx.x] = sh[8];
}

// ---------------------------------------------------------------------------
// Kernel 2: capacity masking. One wave per (b,e): ballot-prefix scan over L.
// Zeroes dropped weights in tok_w in place, accumulates rawsum[b][e].
// ---------------------------------------------------------------------------
__global__ __launch_bounds__(256) void k_capacity(
    const int* __restrict__ tok_idx, float2* __restrict__ tok_w,
    float* __restrict__ rawsum)
{
    const int lane = threadIdx.x & 63;
    const int wid  = (blockIdx.x << 2) + (threadIdx.x >> 6);  // 0..31
    const int b = wid >> 3, e = wid & 7;
    int run = 0; float wsum = 0.f;
    for (int c = 0; c < LL / 64; c++) {
        const int t = b * LL + (c << 6) + lane;
        const int idx = tok_idx[t];
        const float2 w = tok_w[t];
        const int e0 = idx & 0xff, e1 = (idx >> 8) & 0xff;
        const bool is0 = (e0 == e), is1 = (e1 == e);
        const float wv = is0 ? w.x : (is1 ? w.y : 0.f);
        const bool assigned = (is0 | is1) && (wv > 0.f);
        const unsigned long long m = __ballot(assigned);
        const int rank = run + __popcll(m & ((1ull << lane) - 1ull));
        const bool keep = assigned && (rank < CAP);
        if (assigned && !keep) {
            if (is0) tok_w[t].x = 0.f; else tok_w[t].y = 0.f;
        }
        float kv = keep ? wv : 0.f;
        kv += __shfl_xor(kv, 32); kv += __shfl_xor(kv, 16);
        kv += __shfl_xor(kv, 8);  kv += __shfl_xor(kv, 4);
        kv += __shfl_xor(kv, 2);  kv += __shfl_xor(kv, 1);
        wsum += kv;
        run  += __popcll(m);
    }
    if (lane == 0) rawsum[wid] = wsum;
}

// ---------------------------------------------------------------------------
// Kernel 3a: pooled dispatch partials. Grid (128 lchunks, 4 b, 2 dhalf) =
// 1024 blocks (4/CU; was 512 = 2/CU). 32 tokens x 1024 d per block; top-2
// weights expanded to 8-wide rows in LDS; acc[8] float4/thread; no atomics.
// ---------------------------------------------------------------------------
__global__ __launch_bounds__(256) void k_pool(
    const float* __restrict__ x, const int* __restrict__ tok_idx,
    const float2* __restrict__ tok_w, float* __restrict__ pool_part)
{
    __shared__ float dl[32 * 8];
    const int tid = threadIdx.x;
    const int lc = blockIdx.x, b = blockIdx.y, db = blockIdx.z;
    const int l0 = lc * 32;
    if (tid < 32) {
        const int t = b * LL + l0 + tid;
        const int pk = tok_idx[t];
        const float2 w = tok_w[t];
        #pragma unroll
        for (int e = 0; e < 8; e++) dl[tid * 8 + e] = 0.f;
        dl[tid * 8 + (pk & 0xff)] = w.x;
        dl[tid * 8 + ((pk >> 8) & 0xff)] = w.y;
    }
    __syncthreads();
    const int d0 = db * 1024 + tid * 4;
    float4 acc[8];
    #pragma unroll
    for (int e = 0; e < 8; e++) acc[e] = make_float4(0.f, 0.f, 0.f, 0.f);
    #pragma unroll 4
    for (int l = 0; l < 32; l++) {
        const float4 xv = *((const float4*)(x + ((size_t)(b * LL + l0 + l)) * DD + d0));
        const float4 wA = *((const float4*)(dl + l * 8));
        const float4 wB = *((const float4*)(dl + l * 8 + 4));
        acc[0].x += wA.x*xv.x; acc[0].y += wA.x*xv.y; acc[0].z += wA.x*xv.z; acc[0].w += wA.x*xv.w;
        acc[1].x += wA.y*xv.x; acc[1].y += wA.y*xv.y; acc[1].z += wA.y*xv.z; acc[1].w += wA.y*xv.w;
        acc[2].x += wA.z*xv.x; acc[2].y += wA.z*xv.y; acc[2].z += wA.z*xv.z; acc[2].w += wA.z*xv.w;
        acc[3].x += wA.w*xv.x; acc[3].y += wA.w*xv.y; acc[3].z += wA.w*xv.z; acc[3].w += wA.w*xv.w;
        acc[4].x += wB.x*xv.x; acc[4].y += wB.x*xv.y; acc[4].z += wB.x*xv.z; acc[4].w += wB.x*xv.w;
        acc[5].x += wB.y*xv.x; acc[5].y += wB.y*xv.y; acc[5].z += wB.y*xv.z; acc[5].w += wB.y*xv.w;
        acc[6].x += wB.z*xv.x; acc[6].y += wB.z*xv.y; acc[6].z += wB.z*xv.z; acc[6].w += wB.z*xv.w;
        acc[7].x += wB.w*xv.x; acc[7].y += wB.w*xv.y; acc[7].z += wB.w*xv.z; acc[7].w += wB.w*xv.w;
    }
    #pragma unroll
    for (int e = 0; e < 8; e++)
        *((float4*)(pool_part + (((size_t)lc * BB + b) * EE + e) * DD + d0)) = acc[e];
}

// Kernel 3b: reduce the 128 partials and divide by counts.
__global__ __launch_bounds__(256) void k_pool_reduce(
    const float* __restrict__ pool_part, const float* __restrict__ rawsum,
    float* __restrict__ ein)
{
    const int d = blockIdx.x * 256 + threadIdx.x;     // 0..2047
    const int e = blockIdx.y, b = blockIdx.z;
    float s = 0.f;
    #pragma unroll 8
    for (int lc = 0; lc < NLC; lc++)
        s += pool_part[(((size_t)lc * BB + b) * EE + e) * DD + d];
    const float cnt = fmaxf(rawsum[b * EE + e], 1.f);
    ein[((size_t)b * EE + e) * DD + d] = s / cnt;
}

// ---------------------------------------------------------------------------
// Kernel 4: expert GEMM. One wave per output row f; expert inputs (4 x 2048)
// staged in 32KB LDS; each wave computes 4 dots (one per batch) over W row.
// ---------------------------------------------------------------------------
__global__ __launch_bounds__(256) void k_expert(
    const float* __restrict__ ein, const float* __restrict__ eW,
    const float* __restrict__ eb, float* __restrict__ eout)
{
    __shared__ float inl[BB * DD];  // 32KB
    const int tid = threadIdx.x;
    const int e = blockIdx.x >> 9, fb = blockIdx.x & 511;
    #pragma unroll
    for (int i = 0; i < 8; i++) {
        const int idx = tid + i * 256;                 // float4 index, 2048 total
        const int bb = idx >> 9, rem = idx & 511;
        ((float4*)inl)[idx] = ((const float4*)ein)[((size_t)bb * EE + e) * 512 + rem];
    }
    __syncthreads();
    const int wave = tid >> 6, lane = tid & 63;
    const int f = fb * 4 + wave;
    const float4* Wrow = (const float4*)(eW + ((size_t)e * DD + f) * DD);
    float a0 = 0.f, a1 = 0.f, a2 = 0.f, a3 = 0.f;
    #pragma unroll
    for (int j = 0; j < 8; j++) {
        const int fi = lane + j * 64;
        const float4 wv = Wrow[fi];
        const float4 i0 = ((const float4*)(inl + 0 * DD))[fi];
        const float4 i1 = ((const float4*)(inl + 1 * DD))[fi];
        const float4 i2 = ((const float4*)(inl + 2 * DD))[fi];
        const float4 i3 = ((const float4*)(inl + 3 * DD))[fi];
        a0 += wv.x*i0.x + wv.y*i0.y + wv.z*i0.z + wv.w*i0.w;
        a1 += wv.x*i1.x + wv.y*i1.y + wv.z*i1.z + wv.w*i1.w;
        a2 += wv.x*i2.x + wv.y*i2.y + wv.z*i2.z + wv.w*i2.w;
        a3 += wv.x*i3.x + wv.y*i3.y + wv.z*i3.z + wv.w*i3.w;
    }
    a0 += __shfl_xor(a0, 32); a0 += __shfl_xor(a0, 16); a0 += __shfl_xor(a0, 8);
    a0 += __shfl_xor(a0, 4);  a0 += __shfl_xor(a0, 2);  a0 += __shfl_xor(a0, 1);
    a1 += __shfl_xor(a1, 32); a1 += __shfl_xor(a1, 16); a1 += __shfl_xor(a1, 8);
    a1 += __shfl_xor(a1, 4);  a1 += __shfl_xor(a1, 2);  a1 += __shfl_xor(a1, 1);
    a2 += __shfl_xor(a2, 32); a2 += __shfl_xor(a2, 16); a2 += __shfl_xor(a2, 8);
    a2 += __shfl_xor(a2, 4);  a2 += __shfl_xor(a2, 2);  a2 += __shfl_xor(a2, 1);
    a3 += __shfl_xor(a3, 32); a3 += __shfl_xor(a3, 16); a3 += __shfl_xor(a3, 8);
    a3 += __shfl_xor(a3, 4);  a3 += __shfl_xor(a3, 2);  a3 += __shfl_xor(a3, 1);
    if (lane == 0) {
        const float bias = eb[e * DD + f];
        eout[((size_t)0 * EE + e) * DD + f] = a0 + bias;
        eout[((size_t)1 * EE + e) * DD + f] = a1 + bias;
        eout[((size_t)2 * EE + e) * DD + f] = a2 + bias;
        eout[((size_t)3 * EE + e) * DD + f] = a3 + bias;
    }
}

// ---------------------------------------------------------------------------
// Kernel 5: combine (+ fused aux in the one extra block).
// Blocks 0..NTOK-1: out = w0*eout[e0] + w1*eout[e1]. Block NTOK: aux losses.
// ---------------------------------------------------------------------------
__global__ __launch_bounds__(256) void k_combine(
    const int* __restrict__ tok_idx, const float2* __restrict__ tok_w,
    const float* __restrict__ eout, float* __restrict__ out,
    const float* __restrict__ probs_part, const float* __restrict__ ent_part,
    const float* __restrict__ rawsum)
{
    const int t = blockIdx.x;
    if (t < NTOK) {
        const int b = t >> 12;
        const int idx = tok_idx[t];
        const float2 w = tok_w[t];
        const int e0 = idx & 0xff, e1 = (idx >> 8) & 0xff;
        const float4* r0 = (const float4*)(eout + ((size_t)b * EE + e0) * DD);
        const float4* r1 = (const float4*)(eout + ((size_t)b * EE + e1) * DD);
        float4* o = (float4*)(out + (size_t)t * DD);
        #pragma unroll
        for (int j = 0; j < 2; j++) {
            const int i = threadIdx.x + j * 256;
            const float4 p0 = r0[i], p1 = r1[i];
            float4 v;
            v.x = w.x * p0.x + w.y * p1.x;
            v.y = w.x * p0.y + w.y * p1.y;
            v.z = w.x * p0.z + w.y * p1.z;
            v.w = w.x * p0.w + w.y * p1.w;
            o[i] = v;
        }
        return;
    }
    // ---- aux block ----
    __shared__ float sh[256];
    __shared__ float mg[32];
    const int tid = threadIdx.x;
    float es = 0.f;
    if (tid < 64) es = ent_part[tid];
    sh[tid] = es;
    __syncthreads();
    for (int s = 128; s > 0; s >>= 1) {
        if (tid < s) sh[tid] += sh[tid + s];
        __syncthreads();
    }
    if (tid < 32) {
        const int b = tid >> 3, e = tid & 7;
        float s = 0.f;
        #pragma unroll
        for (int k = 0; k < 16; k++) s += probs_part[((size_t)b * 16 + k) * EE + e];
        mg[tid] = s * (1.f / LL);
    }
    __syncthreads();
    if (tid == 0) {
        const float ment = sh[0] * (1.f / NTOK);
        float msum = 0.f;
        #pragma unroll
        for (int i = 0; i < 32; i++) msum += mg[i];
        const float mm = msum / 32.f;
        float v = 0.f;
        #pragma unroll
        for (int i = 0; i < 32; i++) { const float d = mg[i] - mm; v += d * d; }
        float aux = (v / 32.f) * (float)EE;         // population var * E
        float us = 0.f; float util[8];
        #pragma unroll
        for (int e = 0; e < 8; e++) {
            float u = 0.f;
            #pragma unroll
            for (int b = 0; b < 4; b++) u += rawsum[b * 8 + e];
            u *= (1.f / NTOK);
            util[e] = u; us += u;
        }
        const float um = us / 8.f;
        float uv = 0.f;
        #pragma unroll
        for (int e = 0; e < 8; e++) { const float d = util[e] - um; uv += d * d; }
        uv *= (1.f / 7.f);                          // ddof=1
        aux -= uv * 0.01f;
        const float de = ment - 1.0f;
        aux += de * de * 0.01f;
        out[(size_t)NTOK * DD] = aux;
    }
}

// ---------------------------------------------------------------------------
extern "C" void kernel_launch(void* const* d_in, const int* in_sizes, int n_in,
                              void* d_out, int out_size, void* d_ws, size_t ws_size,
                              hipStream_t stream)
{
    const float* x  = (const float*)d_in[0];
    const float* gW = (const float*)d_in[1];
    const float* gb = (const float*)d_in[2];
    const float* ew = (const float*)d_in[3];
    const float* cw = (const float*)d_in[4];
    const float* uw = (const float*)d_in[5];
    const float* tp = (const float*)d_in[6];
    const float* eW = (const float*)d_in[7];
    const float* eb = (const float*)d_in[8];
    float* out = (float*)d_out;

    // workspace layout (floats)
    float*  ws         = (float*)d_ws;
    int*    tok_idx    = (int*)ws;                 // 16384 ints
    float2* tok_w      = (float2*)(ws + 16384);    // 16384 float2
    float*  probs_part = ws + 49152;               // 512 (64 blocks x 8)
    float*  ent_part   = ws + 57344;               // 64
    float*  rawsum     = ws + 58368;               // 32
    float*  ein        = ws + 58432;               // 65536
    float*  eout       = ws + 123968;              // 65536
    float*  gpart      = ws + 189504;              // 524288 (2MB: tok x kc x e)
    // 33.5MB pooling partials live in d_out (fully consumed before k_combine)
    float*  pool_part  = out;

    k_gate_part<<<dim3(1024, 4), 256, 0, stream>>>(x, gW, gpart);
    k_gate_fin<<<64, 256, 0, stream>>>(gpart, gb, ew, cw, uw, tp,
                                       tok_idx, tok_w, probs_part, ent_part);
    k_capacity<<<8, 256, 0, stream>>>(tok_idx, tok_w, rawsum);
    k_pool<<<dim3(NLC, 4, 2), 256, 0, stream>>>(x, tok_idx, tok_w, pool_part);
    k_pool_reduce<<<dim3(8, 8, 4), 256, 0, stream>>>(pool_part, rawsum, ein);
    k_expert<<<4096, 256, 0, stream>>>(ein, eW, eb, eout);
    k_combine<<<NTOK + 1, 256, 0, stream>>>(tok_idx, tok_w, eout, out,
                                            probs_part, ent_part, rawsum);
}